// Round 14
// baseline (73.324 us; speedup 1.0000x reference)
//
#include <hip/hip_runtime.h>
#include <stdint.h>

typedef unsigned long long u64;
typedef unsigned int u32;

#define VOCAB 128000
#define NV4   32000      // VOCAB/4
#define NROWS 256
#define BLK   1024
#define NW    16
#define NB    4096
#define CAPL  8192       // list capacity (all tokens in buckets >= bspec)
#define SEPS  1e-5f
#define LN2X40 27.725887222397812f   /* 40*ln2 */

// ---------- helpers ----------
__device__ __forceinline__ u32 f2key(float f){
  u32 u = __float_as_uint(f);
  return (u & 0x80000000u) ? ~u : (u | 0x80000000u);   // order-preserving
}
__device__ __forceinline__ float key2f(u32 k){
  u32 u = (k & 0x80000000u) ? (k ^ 0x80000000u) : ~k;
  return __uint_as_float(u);
}

// JAX threefry2x32, key (0,42)
__device__ __forceinline__ void tf2x32(u32 x0, u32 x1, u32 &o0, u32 &o1){
  const u32 k0 = 0u, k1 = 42u, k2 = 0u ^ 42u ^ 0x1BD11BDAu;
  x0 += k0; x1 += k1;
#define TFR(r) { x0 += x1; x1 = (x1 << (r)) | (x1 >> (32 - (r))); x1 ^= x0; }
  TFR(13) TFR(15) TFR(26) TFR(6)
  x0 += k1; x1 += k2 + 1u;
  TFR(17) TFR(29) TFR(16) TFR(24)
  x0 += k2; x1 += k0 + 2u;
  TFR(13) TFR(15) TFR(26) TFR(6)
  x0 += k0; x1 += k1 + 3u;
  TFR(17) TFR(29) TFR(16) TFR(24)
  x0 += k1; x1 += k2 + 4u;
  TFR(13) TFR(15) TFR(26) TFR(6)
  x0 += k2; x1 += k0 + 5u;
#undef TFR
  o0 = x0; o1 = x1;
}
__device__ __forceinline__ u32 gumbel_bits(u32 i){
  u32 o0, o1; tf2x32(0u, i, o0, o1);
  return o0 ^ o1;
}
__device__ __forceinline__ float bits2gumbel(u32 b){
  float f = __uint_as_float(0x3F800000u | (b >> 9)) - 1.0f;  // [0,1)
  float u = fmaxf(1e-10f, f + 1e-10f);
  return -logf(-logf(u));
}

// ---------- crossing searches (reduce + wave-0 descent) ----------
__device__ __forceinline__ void cross4096_u32(
    const u32* arr, u32* aux, u32 target, u32* out_idx, u32* out_before, int t)
{
  aux[t] = arr[4*t+0] + arr[4*t+1] + arr[4*t+2] + arr[4*t+3];
  __syncthreads();
  if (t < 64){
    u32 gs = 0u;
    #pragma unroll
    for (int j=0;j<16;j++) gs += aux[t*16+j];
    u32 pref = gs;
    #pragma unroll
    for (int d=1; d<64; d<<=1){ u32 v = __shfl_up(pref, d, 64); if (t >= d) pref += v; }
    u64 bal = __ballot(pref > target);
    int g = bal ? (__ffsll((long long)bal) - 1) : 63;
    u32 pg = __shfl(pref, g, 64);
    u32 gg = __shfl(gs, g, 64);
    if (t == 0){
      u32 c = pg - gg;
      u32 idx = (u32)(g*64 + 63);
      for (int j=0;j<16;j++){
        u32 v = aux[g*16+j];
        if (c + v > target){
          int base = (g*16+j)*4;
          for (int q=0;q<4;q++){
            u32 w = arr[base+q];
            if (c + w > target){ idx = (u32)(base+q); goto doneu; }
            c += w;
          }
        }
        c += v;
      }
      doneu:
      *out_idx = idx; *out_before = c;
    }
  }
}

__device__ __forceinline__ void cross4096_u64(
    const u64* arr, u64* aux, u64 target, u32* out_idx, u64* out_before, int t)
{
  aux[t] = arr[4*t+0] + arr[4*t+1] + arr[4*t+2] + arr[4*t+3];
  __syncthreads();
  if (t < 64){
    u64 gs = 0ull;
    #pragma unroll
    for (int j=0;j<16;j++) gs += aux[t*16+j];
    u64 pref = gs;
    #pragma unroll
    for (int d=1; d<64; d<<=1){
      u64 v = __shfl_up((unsigned long long)pref, d, 64); if (t >= d) pref += v;
    }
    u64 bal = __ballot(pref > target);
    int g = bal ? (__ffsll((long long)bal) - 1) : 63;
    u64 pg = __shfl((unsigned long long)pref, g, 64);
    u64 gg = __shfl((unsigned long long)gs, g, 64);
    if (t == 0){
      u64 c = pg - gg;
      u32 idx = (u32)(g*64 + 63);
      for (int j=0;j<16;j++){
        u64 v = aux[g*16+j];
        if (c + v > target){
          int base = (g*16+j)*4;
          for (int q=0;q<4;q++){
            u64 w = arr[base+q];
            if (c + w > target){ idx = (u32)(base+q); goto donev; }
            c += w;
          }
        }
        c += v;
      }
      donev:
      *out_idx = idx; *out_before = c;
    }
  }
}

// level-1 mass: derives total and target = (1-topp)*total internally
__device__ __forceinline__ void cross4096_mass(
    const u64* arr, u64* aux, float topp_v, u64* out_target,
    u32* out_idx, u64* out_before, int t)
{
  aux[t] = arr[4*t+0] + arr[4*t+1] + arr[4*t+2] + arr[4*t+3];
  __syncthreads();
  if (t < 64){
    u64 gs = 0ull;
    #pragma unroll
    for (int j=0;j<16;j++) gs += aux[t*16+j];
    u64 pref = gs;
    #pragma unroll
    for (int d=1; d<64; d<<=1){
      u64 v = __shfl_up((unsigned long long)pref, d, 64); if (t >= d) pref += v;
    }
    u64 total = __shfl((unsigned long long)pref, 63, 64);
    u64 target = (u64)((double)(1.0f - topp_v) * (double)total);
    u64 bal = __ballot(pref > target);
    int g = bal ? (__ffsll((long long)bal) - 1) : 63;
    u64 pg = __shfl((unsigned long long)pref, g, 64);
    u64 gg = __shfl((unsigned long long)gs, g, 64);
    if (t == 0){
      u64 c = pg - gg;
      u32 idx = (u32)(g*64 + 63);
      for (int j=0;j<16;j++){
        u64 v = aux[g*16+j];
        if (c + v > target){
          int base = (g*16+j)*4;
          for (int q=0;q<4;q++){
            u64 w = arr[base+q];
            if (c + w > target){ idx = (u32)(base+q); goto donem; }
            c += w;
          }
        }
        c += v;
      }
      donem:
      *out_target = target; *out_idx = idx; *out_before = c;
    }
  }
}

__device__ __forceinline__ void cross256_u32(const u32* arr, u32 target, u32* out_idx, int t){
  if (t < 64){
    u32 gs = arr[4*t+0]+arr[4*t+1]+arr[4*t+2]+arr[4*t+3];
    u32 pref = gs;
    #pragma unroll
    for (int d=1; d<64; d<<=1){ u32 v=__shfl_up(pref,d,64); if (t>=d) pref+=v; }
    u64 bal = __ballot(pref > target);
    int g = bal ? (__ffsll((long long)bal)-1) : 63;
    u32 pg=__shfl(pref,g,64), gg=__shfl(gs,g,64);
    if (t==0){
      u32 c = pg-gg; u32 idx=(u32)(g*4+3);
      for (int q=0;q<4;q++){ u32 w=arr[g*4+q]; if (c+w>target){ idx=(u32)(g*4+q); break; } c+=w; }
      *out_idx = idx;
    }
  }
}
__device__ __forceinline__ void cross256_u64(const u64* arr, u64 target, u32* out_idx, int t){
  if (t < 64){
    u64 gs = arr[4*t+0]+arr[4*t+1]+arr[4*t+2]+arr[4*t+3];
    u64 pref = gs;
    #pragma unroll
    for (int d=1; d<64; d<<=1){
      u64 v=__shfl_up((unsigned long long)pref,d,64); if (t>=d) pref+=v;
    }
    u64 bal = __ballot(pref > target);
    int g = bal ? (__ffsll((long long)bal)-1) : 63;
    u64 pg=__shfl((unsigned long long)pref,g,64), gg=__shfl((unsigned long long)gs,g,64);
    if (t==0){
      u64 c = pg-gg; u32 idx=(u32)(g*4+3);
      for (int q=0;q<4;q++){ u64 w=arr[g*4+q]; if (c+w>target){ idx=(u32)(g*4+q); break; } c+=w; }
      *out_idx = idx;
    }
  }
}

// block argmax (larger value, then smaller idx) -> out[b]
__device__ __forceinline__ void argmax_write(
    float best, u32 bi, float* wrf, u32* wru, int ln, int wv, int b, int* out)
{
  #pragma unroll
  for (int d=32; d>0; d>>=1){
    float c2=__shfl_down(best,d,64); u32 i2=__shfl_down(bi,d,64);
    if (c2>best || (c2==best && i2<bi)){best=c2;bi=i2;}
  }
  if (ln==0){ wrf[wv]=best; wru[wv]=bi; }
  __syncthreads();
  if (wv==0){
    float b1=(ln<NW)?wrf[ln]:-INFINITY; u32 i1=(ln<NW)?wru[ln]:0xFFFFFFFFu;
    #pragma unroll
    for (int d=32; d>0; d>>=1){
      float b2=__shfl_down(b1,d,64); u32 i2=__shfl_down(i1,d,64);
      if (b2>b1 || (b2==b1 && i2<i1)){b1=b2;i1=i2;}
    }
    if (ln==0) out[b]=(int)i1;
  }
}

// ---------- fused kernel: one block per row ----------
__global__ __launch_bounds__(BLK) void k_all(
    const float* __restrict__ logits, const float* __restrict__ temp,
    const float* __restrict__ minp, const int* __restrict__ topk,
    const float* __restrict__ topp, int* __restrict__ out)
{
  __shared__ u32 cnt[NB];          // 16KB (sparse: buckets >= bspec)
  __shared__ u64 massI[NB];        // 32KB
  __shared__ u64 list[CAPL];       // 64KB: (key<<32)|idx, all tokens of buckets >= bspec
  __shared__ u64 aux64[BLK];       // 8KB scratch (u32-punned too)
  __shared__ float wrf1[NW];
  __shared__ u32  wru1[NW], wru2[NW];
  __shared__ u32 sh_kmax, sh_lstar, sh_len, sh_idx, sh_bef32;
  __shared__ float sh_Z;
  __shared__ u64 sh_bef64, sh_tfix;

  u32* aux32 = (u32*)aux64;

  const int b = blockIdx.x;
  const int t = threadIdx.x;
  const int ln = t & 63, wv = t >> 6;
  const float T = temp[b];
  const float* row = logits + (size_t)b * VOCAB;
  const float4* row4 = (const float4*)row;

  // ======== greedy rows: argmax only (1 stream) ========
  if (T < SEPS){
    float M = -INFINITY; u32 Mi = 0xFFFFFFFFu;
    for (int i=t; i<NV4; i+=BLK){
      float4 q = row4[i];
      #pragma unroll
      for (int j=0;j<4;j++){
        float l = (&q.x)[j]; u32 gi = (u32)(i*4+j);
        if (l > M){ M = l; Mi = gi; }
      }
    }
    argmax_write(M, Mi, wrf1, wru1, ln, wv, b, out);
    return;
  }
  const float invT = 1.0f / T;

  // ======== S0: 2048-point sample -> bspec (bucket of ~2000th-largest) ========
  for (int i=t;i<NB;i+=BLK) cnt[i]=0u;
  if (t==0) sh_len=0u;
  __syncthreads();
  for (int s=t; s<2048; s+=BLK){
    int c = s >> 6, j = s & 63;
    atomicAdd(&cnt[f2key(row[c*4000 + j])>>20], 1u);
  }
  __syncthreads();
  cross4096_u32(cnt, aux32, 2016u, &sh_idx, &sh_bef32, t);  // 32nd-from-top sample
  __syncthreads();
  const u32 bspec = sh_idx;
  const u32 keyspec = bspec << 20;
  __syncthreads();
  for (int i=t;i<NB;i+=BLK){ cnt[i]=0u; massI[i]=0ull; }
  __syncthreads();

  // ======== P1: key-max + Z sum (all) + sparse count hist + list (rare) ========
  u32 km = 0u;
  float S0=0.0f,S1=0.0f,S2=0.0f,S3=0.0f;
#define P1E(LV, SS, IDX) { \
    float l_ = (LV); u32 k_ = f2key(l_); \
    if (k_ > km) km = k_; \
    SS += __expf(l_ * invT); \
    bool cand_ = (k_ >= keyspec); \
    u64 bal_ = __ballot(cand_); \
    if (cand_){ \
      atomicAdd(&cnt[k_>>20], 1u); \
      u32 lead_ = (u32)__ffsll((long long)bal_) - 1u; \
      u32 base_ = 0u; \
      if ((u32)ln == lead_) base_ = atomicAdd(&sh_len, (u32)__popcll(bal_)); \
      base_ = __shfl(base_, (int)lead_, 64); \
      u32 p_ = base_ + (u32)__popcll(bal_ & ((1ull << ln) - 1ull)); \
      if (p_ < CAPL) list[p_] = ((u64)k_ << 32) | (u64)(u32)(IDX); \
    } }
  for (int i=t; i<NV4; i+=2*BLK){
    float4 qa = row4[i];
    int i2 = i + BLK; bool h2 = (i2 < NV4);
    float4 qb; if (h2) qb = row4[i2];
    P1E(qa.x,S0,i*4+0) P1E(qa.y,S1,i*4+1) P1E(qa.z,S2,i*4+2) P1E(qa.w,S3,i*4+3)
    if (h2){
      P1E(qb.x,S0,i2*4+0) P1E(qb.y,S1,i2*4+1) P1E(qb.z,S2,i2*4+2) P1E(qb.w,S3,i2*4+3)
    }
  }
#undef P1E
  float S = (S0+S1)+(S2+S3);
  #pragma unroll
  for (int d=32; d>0; d>>=1){
    S += __shfl_down(S, d, 64);
    u32 k2 = __shfl_down(km, d, 64); if (k2 > km) km = k2;
  }
  if (ln==0){ wrf1[wv]=S; wru1[wv]=km; }
  __syncthreads();                        // orders hist atomics + sh_len
  if (t==0){
    float St=0.0f; u32 kt=0u;
    for (int w=0; w<NW; w++){ St += wrf1[w]; if (wru1[w]>kt) kt=wru1[w]; }
    sh_kmax = kt;
    sh_Z = St;
  }
  __syncthreads();
  const float m = key2f(sh_kmax) * invT;
  const float Z = sh_Z * __expf(-m);
  const u32 Nc = sh_len;                  // exact count of tokens in buckets >= bspec

  int tk = topk[b]; if (tk < 1) tk = 1; if (tk > VOCAB) tk = VOCAB;
  const bool sampleOK = (Nc >= (u32)tk);
  u32 NcEff = Nc;
  if (!sampleOK){
    // corrective full count hist (~never taken)
    __syncthreads();
    for (int i=t;i<NB;i+=BLK) cnt[i]=0u;
    __syncthreads();
    for (int i=t; i<NV4; i+=BLK){
      float4 q = row4[i];
      #pragma unroll
      for (int j=0;j<4;j++) atomicAdd(&cnt[f2key((&q.x)[j])>>20], 1u);
    }
    __syncthreads();
    NcEff = (u32)VOCAB;
  }

  // ---- top-k level-1 crossing over counted hist ----
  cross4096_u32(cnt, aux32, NcEff - (u32)tk, &sh_idx, &sh_bef32, t);
  __syncthreads();
  const u32 b1k = sh_idx;
  const u32 r1  = (NcEff - (u32)tk + 1u) - sh_bef32;

  // ---- min-p raw cutoff l*: wave-parallel monotone search ----
  if (wv==0){
    const float rhs = minp[b] * (1.0f / Z);
    u32 lo = 0u, hi = 0xFF800000u;       // pred(hi)=true; pred(0)=false (NaN key)
    while (hi - lo > 64u){
      u32 step = (hi - lo) >> 6;
      u32 k = lo + (u32)(ln + 1) * step;
      float e = __expf(fmaf(key2f(k), invT, -m));
      u64 bal = __ballot((e / Z) >= rhs);
      if (bal){
        u32 g = (u32)(__ffsll((long long)bal) - 1);
        hi = lo + (g + 1u) * step;
        lo = lo + g * step;
      } else {
        lo += 64u * step;
      }
    }
    u32 k = lo + 1u + (u32)ln;
    bool ok = (k <= hi);
    float e = __expf(fmaf(key2f(k), invT, -m));
    u64 bal = __ballot(ok && ((e / Z) >= rhs));
    if (ln==0) sh_lstar = bal ? (lo + 1u + (u32)(__ffsll((long long)bal) - 1)) : hi;
  }
  __syncthreads();
  const u32 lstar = sh_lstar;
  const bool fastOK = sampleOK && (Nc <= (u32)CAPL);
  const float cs = LN2X40 - m;           // (u64)expf(l*invT + cs) = e^(s-m)*2^40

  // ======== P2: filtered mass hist + K (no list work) ========
  u32 kc = 0u;
#define P2E(LV) { \
    float l_ = (LV); u32 key_ = f2key(l_); \
    if (key_ >= lstar){ \
      kc++; \
      u64 lm_ = (u64)__expf(fmaf(l_, invT, cs)); \
      if (lm_) atomicAdd(&massI[key_>>20], lm_); \
    } }
  for (int i=t; i<NV4; i+=2*BLK){
    float4 qa = row4[i];
    int i2 = i + BLK; bool h2 = (i2 < NV4);
    float4 qb; if (h2) qb = row4[i2];
    P2E(qa.x) P2E(qa.y) P2E(qa.z) P2E(qa.w)
    if (h2){ P2E(qb.x) P2E(qb.y) P2E(qb.z) P2E(qb.w) }
  }
#undef P2E
  #pragma unroll
  for (int d=32; d>0; d>>=1) kc += __shfl_down(kc, d, 64);
  if (ln==0) wru2[wv] = kc;
  __syncthreads();                        // P2 atomics complete here
  if (t==0){ u32 K2=0u; for (int w=0;w<NW;w++) K2 += wru2[w]; wru2[0] = K2; }
  __syncthreads();
  const u32 K = wru2[0];
  const bool kval = (K >= (u32)tk);

  cross4096_mass(massI, aux64, topp[b], &sh_tfix, &sh_idx, &sh_bef64, t);
  __syncthreads();
  const u32 b1p = sh_idx;
  const u64 t1  = sh_tfix - sh_bef64;
  const bool needK = kval && (b1p <= b1k);
  const bool needP = (!kval) || (b1p >= b1k);

  u32 kkey = 0u, pkey = 0u;

  if (fastOK){
    const u32 llen = Nc;
    // ---- k-refine from list ----
    if (needK){
      for (int i=t;i<NB;i+=BLK) cnt[i]=0u;
      __syncthreads();
      for (u32 i=t; i<llen; i+=BLK){
        u32 key = (u32)(list[i]>>32);
        if ((key>>20) == b1k) atomicAdd(&cnt[(key>>8)&0xFFFu], 1u);
      }
      __syncthreads();
      cross4096_u32(cnt, aux32, r1-1u, &sh_idx, &sh_bef32, t);
      __syncthreads();
      u32 b2k = sh_idx, r2 = r1 - sh_bef32;
      u32 prefk = (b1k<<12) | b2k;
      for (int i=t;i<256;i+=BLK) cnt[i]=0u;
      __syncthreads();
      for (u32 i=t; i<llen; i+=BLK){
        u32 key = (u32)(list[i]>>32);
        if ((key>>8) == prefk) atomicAdd(&cnt[key&0xFFu], 1u);
      }
      __syncthreads();
      cross256_u32(cnt, r2-1u, &sh_idx, t);
      __syncthreads();
      kkey = (prefk<<8) | sh_idx;
    }
    // ---- p-refine from list ----
    if (needP){
      for (int i=t;i<NB;i+=BLK) massI[i]=0ull;
      __syncthreads();
      for (u32 i=t; i<llen; i+=BLK){
        u32 key = (u32)(list[i]>>32);
        if ((key>>20) == b1p && key >= lstar){
          u64 lm = (u64)__expf(fmaf(key2f(key), invT, cs));
          if (lm) atomicAdd(&massI[(key>>8)&0xFFFu], lm);
        }
      }
      __syncthreads();
      cross4096_u64(massI, aux64, t1, &sh_idx, &sh_bef64, t);
      __syncthreads();
      u32 b2p = sh_idx; u64 t2 = t1 - sh_bef64;
      u32 prefp = (b1p<<12) | b2p;
      for (int i=t;i<256;i+=BLK) massI[i]=0ull;
      __syncthreads();
      for (u32 i=t; i<llen; i+=BLK){
        u32 key = (u32)(list[i]>>32);
        if ((key>>8) == prefp && key >= lstar){
          u64 lm = (u64)__expf(fmaf(key2f(key), invT, cs));
          if (lm) atomicAdd(&massI[key&0xFFu], lm);
        }
      }
      __syncthreads();
      cross256_u64(massI, t2, &sh_idx, t);
      __syncthreads();
      pkey = (prefp<<8) | sh_idx;
    }
    const u32 thrkey = kkey > pkey ? kkey : pkey;

    // ---- sampling over list (survivors <= ~63; all survivors are in list) ----
    float best = -INFINITY; u32 bi = 0xFFFFFFFFu;
    for (u32 i=t; i<llen; i+=BLK){
      u64 e = list[i];
      u32 key = (u32)(e>>32);
      if (key >= thrkey){
        u32 idx = (u32)e;
        u32 c = (u32)b * (u32)VOCAB + idx;
        float cand = key2f(key)*invT + bits2gumbel(gumbel_bits(c));
        if (cand > best || (cand == best && idx < bi)){ best = cand; bi = idx; }
      }
    }
    argmax_write(best, bi, wrf1, wru1, ln, wv, b, out);
    return;
  }

  // ======== slow path (overflow / sample failure): full-stream refinement ========
  for (int i=t;i<NB;i+=BLK){ cnt[i]=0u; massI[i]=0ull; }
  __syncthreads();
  for (int i=t; i<NV4; i+=BLK){
    float4 q = row4[i];
    #pragma unroll
    for (int j=0;j<4;j++){
      float l = (&q.x)[j]; u32 key = f2key(l); u32 hb = key>>20;
      if (needK && hb == b1k) atomicAdd(&cnt[(key>>8)&0xFFFu], 1u);
      if (needP && hb == b1p && key >= lstar){
        u64 lm = (u64)__expf(fmaf(l, invT, cs));
        if (lm) atomicAdd(&massI[(key>>8)&0xFFFu], lm);
      }
    }
  }
  __syncthreads();
  u32 b2k = 0u, r2 = 1u, b2p = 0u; u64 t2 = 0ull;
  if (needK){
    cross4096_u32(cnt, aux32, r1-1u, &sh_idx, &sh_bef32, t);
    __syncthreads();
    b2k = sh_idx; r2 = r1 - sh_bef32;
  }
  if (needP){
    cross4096_u64(massI, aux64, t1, &sh_idx, &sh_bef64, t);
    __syncthreads();
    b2p = sh_idx; t2 = t1 - sh_bef64;
  }
  const u32 prefk = (b1k<<12) | b2k;
  const u32 prefp = (b1p<<12) | b2p;
  for (int i=t;i<256;i+=BLK){ cnt[i]=0u; massI[i]=0ull; }
  __syncthreads();
  for (int i=t; i<NV4; i+=BLK){
    float4 q = row4[i];
    #pragma unroll
    for (int j=0;j<4;j++){
      float l = (&q.x)[j]; u32 key = f2key(l);
      if (needK && (key>>8) == prefk) atomicAdd(&cnt[key&0xFFu], 1u);
      if (needP && (key>>8) == prefp && key >= lstar){
        u64 lm = (u64)__expf(fmaf(l, invT, cs));
        if (lm) atomicAdd(&massI[key&0xFFu], lm);
      }
    }
  }
  __syncthreads();
  if (needK){
    cross256_u32(cnt, r2-1u, &sh_idx, t);
    __syncthreads();
    kkey = (prefk<<8) | sh_idx;
  }
  if (needP){
    cross256_u64(massI, t2, &sh_idx, t);
    __syncthreads();
    pkey = (prefp<<8) | sh_idx;
  }
  const float thrf = key2f(kkey > pkey ? kkey : pkey);
  float best = -INFINITY; u32 bi = 0xFFFFFFFFu;
  for (int i=t; i<NV4; i+=BLK){
    float4 q = row4[i];
    #pragma unroll
    for (int j=0;j<4;j++){
      float l = (&q.x)[j];
      if (l >= thrf){
        u32 idx = (u32)(i*4+j);
        u32 c = (u32)b * (u32)VOCAB + idx;
        float cand = l*invT + bits2gumbel(gumbel_bits(c));
        if (cand > best || (cand == best && idx < bi)){ best = cand; bi = idx; }
      }
    }
  }
  argmax_write(best, bi, wrf1, wru1, ln, wv, b, out);
}

extern "C" void kernel_launch(void* const* d_in, const int* in_sizes, int n_in,
                              void* d_out, int out_size, void* d_ws, size_t ws_size,
                              hipStream_t stream)
{
  const float* logits = (const float*)d_in[0];
  const float* temp   = (const float*)d_in[1];
  const float* minp   = (const float*)d_in[2];
  const int*   topk   = (const int*)d_in[3];
  const float* topp   = (const float*)d_in[4];
  int* out = (int*)d_out;

  hipLaunchKernelGGL(k_all, dim3(NROWS), dim3(BLK), 0, stream,
                     logits, temp, minp, topk, topp, out);
}

// Round 15
// 65.157 us; speedup vs baseline: 1.1253x; 1.1253x over previous
//
#include <hip/hip_runtime.h>
#include <stdint.h>

typedef unsigned long long u64;
typedef unsigned int u32;

#define VOCAB 128000
#define NV4   32000      // VOCAB/4
#define NROWS 256
#define BLK   1024
#define NW    16
#define NB    4096
#define CAPL  8192       // list capacity (all tokens in buckets >= bspec)
#define SEPS  1e-5f
#define LN2X40 27.725887222397812f   /* 40*ln2 */

// ---------- helpers ----------
__device__ __forceinline__ u32 f2key(float f){
  u32 u = __float_as_uint(f);
  return (u & 0x80000000u) ? ~u : (u | 0x80000000u);   // order-preserving
}
__device__ __forceinline__ float key2f(u32 k){
  u32 u = (k & 0x80000000u) ? (k ^ 0x80000000u) : ~k;
  return __uint_as_float(u);
}

// JAX threefry2x32, key (0,42)
__device__ __forceinline__ void tf2x32(u32 x0, u32 x1, u32 &o0, u32 &o1){
  const u32 k0 = 0u, k1 = 42u, k2 = 0u ^ 42u ^ 0x1BD11BDAu;
  x0 += k0; x1 += k1;
#define TFR(r) { x0 += x1; x1 = (x1 << (r)) | (x1 >> (32 - (r))); x1 ^= x0; }
  TFR(13) TFR(15) TFR(26) TFR(6)
  x0 += k1; x1 += k2 + 1u;
  TFR(17) TFR(29) TFR(16) TFR(24)
  x0 += k2; x1 += k0 + 2u;
  TFR(13) TFR(15) TFR(26) TFR(6)
  x0 += k0; x1 += k1 + 3u;
  TFR(17) TFR(29) TFR(16) TFR(24)
  x0 += k1; x1 += k2 + 4u;
  TFR(13) TFR(15) TFR(26) TFR(6)
  x0 += k2; x1 += k0 + 5u;
#undef TFR
  o0 = x0; o1 = x1;
}
__device__ __forceinline__ u32 gumbel_bits(u32 i){
  u32 o0, o1; tf2x32(0u, i, o0, o1);
  return o0 ^ o1;
}
__device__ __forceinline__ float bits2gumbel(u32 b){
  float f = __uint_as_float(0x3F800000u | (b >> 9)) - 1.0f;  // [0,1)
  float u = fmaxf(1e-10f, f + 1e-10f);
  return -logf(-logf(u));
}

// ---------- crossing searches (reduce + wave-0 descent) ----------
__device__ __forceinline__ void cross4096_u32(
    const u32* arr, u32* aux, u32 target, u32* out_idx, u32* out_before, int t)
{
  aux[t] = arr[4*t+0] + arr[4*t+1] + arr[4*t+2] + arr[4*t+3];
  __syncthreads();
  if (t < 64){
    u32 gs = 0u;
    #pragma unroll
    for (int j=0;j<16;j++) gs += aux[t*16+j];
    u32 pref = gs;
    #pragma unroll
    for (int d=1; d<64; d<<=1){ u32 v = __shfl_up(pref, d, 64); if (t >= d) pref += v; }
    u64 bal = __ballot(pref > target);
    int g = bal ? (__ffsll((long long)bal) - 1) : 63;
    u32 pg = __shfl(pref, g, 64);
    u32 gg = __shfl(gs, g, 64);
    if (t == 0){
      u32 c = pg - gg;
      u32 idx = (u32)(g*64 + 63);
      for (int j=0;j<16;j++){
        u32 v = aux[g*16+j];
        if (c + v > target){
          int base = (g*16+j)*4;
          for (int q=0;q<4;q++){
            u32 w = arr[base+q];
            if (c + w > target){ idx = (u32)(base+q); goto doneu; }
            c += w;
          }
        }
        c += v;
      }
      doneu:
      *out_idx = idx; *out_before = c;
    }
  }
}

__device__ __forceinline__ void cross4096_u64(
    const u64* arr, u64* aux, u64 target, u32* out_idx, u64* out_before, int t)
{
  aux[t] = arr[4*t+0] + arr[4*t+1] + arr[4*t+2] + arr[4*t+3];
  __syncthreads();
  if (t < 64){
    u64 gs = 0ull;
    #pragma unroll
    for (int j=0;j<16;j++) gs += aux[t*16+j];
    u64 pref = gs;
    #pragma unroll
    for (int d=1; d<64; d<<=1){
      u64 v = __shfl_up((unsigned long long)pref, d, 64); if (t >= d) pref += v;
    }
    u64 bal = __ballot(pref > target);
    int g = bal ? (__ffsll((long long)bal) - 1) : 63;
    u64 pg = __shfl((unsigned long long)pref, g, 64);
    u64 gg = __shfl((unsigned long long)gs, g, 64);
    if (t == 0){
      u64 c = pg - gg;
      u32 idx = (u32)(g*64 + 63);
      for (int j=0;j<16;j++){
        u64 v = aux[g*16+j];
        if (c + v > target){
          int base = (g*16+j)*4;
          for (int q=0;q<4;q++){
            u64 w = arr[base+q];
            if (c + w > target){ idx = (u32)(base+q); goto donev; }
            c += w;
          }
        }
        c += v;
      }
      donev:
      *out_idx = idx; *out_before = c;
    }
  }
}

// level-1 mass: derives total and target = (1-topp)*total internally
__device__ __forceinline__ void cross4096_mass(
    const u64* arr, u64* aux, float topp_v, u64* out_target,
    u32* out_idx, u64* out_before, int t)
{
  aux[t] = arr[4*t+0] + arr[4*t+1] + arr[4*t+2] + arr[4*t+3];
  __syncthreads();
  if (t < 64){
    u64 gs = 0ull;
    #pragma unroll
    for (int j=0;j<16;j++) gs += aux[t*16+j];
    u64 pref = gs;
    #pragma unroll
    for (int d=1; d<64; d<<=1){
      u64 v = __shfl_up((unsigned long long)pref, d, 64); if (t >= d) pref += v;
    }
    u64 total = __shfl((unsigned long long)pref, 63, 64);
    u64 target = (u64)((double)(1.0f - topp_v) * (double)total);
    u64 bal = __ballot(pref > target);
    int g = bal ? (__ffsll((long long)bal) - 1) : 63;
    u64 pg = __shfl((unsigned long long)pref, g, 64);
    u64 gg = __shfl((unsigned long long)gs, g, 64);
    if (t == 0){
      u64 c = pg - gg;
      u32 idx = (u32)(g*64 + 63);
      for (int j=0;j<16;j++){
        u64 v = aux[g*16+j];
        if (c + v > target){
          int base = (g*16+j)*4;
          for (int q=0;q<4;q++){
            u64 w = arr[base+q];
            if (c + w > target){ idx = (u32)(base+q); goto donem; }
            c += w;
          }
        }
        c += v;
      }
      donem:
      *out_target = target; *out_idx = idx; *out_before = c;
    }
  }
}

__device__ __forceinline__ void cross256_u32(const u32* arr, u32 target, u32* out_idx, int t){
  if (t < 64){
    u32 gs = arr[4*t+0]+arr[4*t+1]+arr[4*t+2]+arr[4*t+3];
    u32 pref = gs;
    #pragma unroll
    for (int d=1; d<64; d<<=1){ u32 v=__shfl_up(pref,d,64); if (t>=d) pref+=v; }
    u64 bal = __ballot(pref > target);
    int g = bal ? (__ffsll((long long)bal)-1) : 63;
    u32 pg=__shfl(pref,g,64), gg=__shfl(gs,g,64);
    if (t==0){
      u32 c = pg-gg; u32 idx=(u32)(g*4+3);
      for (int q=0;q<4;q++){ u32 w=arr[g*4+q]; if (c+w>target){ idx=(u32)(g*4+q); break; } c+=w; }
      *out_idx = idx;
    }
  }
}
__device__ __forceinline__ void cross256_u64(const u64* arr, u64 target, u32* out_idx, int t){
  if (t < 64){
    u64 gs = arr[4*t+0]+arr[4*t+1]+arr[4*t+2]+arr[4*t+3];
    u64 pref = gs;
    #pragma unroll
    for (int d=1; d<64; d<<=1){
      u64 v=__shfl_up((unsigned long long)pref,d,64); if (t>=d) pref+=v;
    }
    u64 bal = __ballot(pref > target);
    int g = bal ? (__ffsll((long long)bal)-1) : 63;
    u64 pg=__shfl((unsigned long long)pref,g,64), gg=__shfl((unsigned long long)gs,g,64);
    if (t==0){
      u64 c = pg-gg; u32 idx=(u32)(g*4+3);
      for (int q=0;q<4;q++){ u64 w=arr[g*4+q]; if (c+w>target){ idx=(u32)(g*4+q); break; } c+=w; }
      *out_idx = idx;
    }
  }
}

// block argmax (larger value, then smaller idx) -> out[b]
__device__ __forceinline__ void argmax_write(
    float best, u32 bi, float* wrf, u32* wru, int ln, int wv, int b, int* out)
{
  #pragma unroll
  for (int d=32; d>0; d>>=1){
    float c2=__shfl_down(best,d,64); u32 i2=__shfl_down(bi,d,64);
    if (c2>best || (c2==best && i2<bi)){best=c2;bi=i2;}
  }
  if (ln==0){ wrf[wv]=best; wru[wv]=bi; }
  __syncthreads();
  if (wv==0){
    float b1=(ln<NW)?wrf[ln]:-INFINITY; u32 i1=(ln<NW)?wru[ln]:0xFFFFFFFFu;
    #pragma unroll
    for (int d=32; d>0; d>>=1){
      float b2=__shfl_down(b1,d,64); u32 i2=__shfl_down(i1,d,64);
      if (b2>b1 || (b2==b1 && i2<i1)){b1=b2;i1=i2;}
    }
    if (ln==0) out[b]=(int)i1;
  }
}

// ---------- fused kernel: one block per row ----------
__global__ __launch_bounds__(BLK) void k_all(
    const float* __restrict__ logits, const float* __restrict__ temp,
    const float* __restrict__ minp, const int* __restrict__ topk,
    const float* __restrict__ topp, int* __restrict__ out)
{
  __shared__ u32 cnt[NB];          // 16KB (sparse: buckets >= bspec)
  __shared__ u64 massI[NB];        // 32KB
  __shared__ u64 list[CAPL];       // 64KB: (key<<32)|idx, all tokens of buckets >= bspec
  __shared__ u64 aux64[BLK];       // 8KB scratch (u32-punned too)
  __shared__ float wrf1[NW];
  __shared__ u32  wru1[NW], wru2[NW];
  __shared__ u32 sh_kmax, sh_lstar, sh_len, sh_idx, sh_bef32;
  __shared__ float sh_Z;
  __shared__ u64 sh_bef64, sh_tfix;

  u32* aux32 = (u32*)aux64;

  const int b = blockIdx.x;
  const int t = threadIdx.x;
  const int ln = t & 63, wv = t >> 6;
  const float T = temp[b];
  const float* row = logits + (size_t)b * VOCAB;
  const float4* row4 = (const float4*)row;

  // ======== greedy rows: argmax only (1 stream) ========
  if (T < SEPS){
    float M = -INFINITY; u32 Mi = 0xFFFFFFFFu;
    for (int i=t; i<NV4; i+=BLK){
      float4 q = row4[i];
      #pragma unroll
      for (int j=0;j<4;j++){
        float l = (&q.x)[j]; u32 gi = (u32)(i*4+j);
        if (l > M){ M = l; Mi = gi; }
      }
    }
    argmax_write(M, Mi, wrf1, wru1, ln, wv, b, out);
    return;
  }
  const float invT = 1.0f / T;

  // ======== S0: 2048-point sample -> bspec (bucket of ~2000th-largest) ========
  for (int i=t;i<NB;i+=BLK) cnt[i]=0u;
  if (t==0) sh_len=0u;
  __syncthreads();
  for (int s=t; s<2048; s+=BLK){
    int c = s >> 6, j = s & 63;
    atomicAdd(&cnt[f2key(row[c*4000 + j])>>20], 1u);
  }
  __syncthreads();
  cross4096_u32(cnt, aux32, 2016u, &sh_idx, &sh_bef32, t);  // 32nd-from-top sample
  __syncthreads();
  const u32 bspec = sh_idx;
  const u32 keyspec = bspec << 20;
  __syncthreads();
  for (int i=t;i<NB;i+=BLK){ cnt[i]=0u; massI[i]=0ull; }
  __syncthreads();

  // ======== P1: key-max + Z sum (all) + sparse hist + list (plain guard, rare) ========
  u32 km = 0u;
  float S0=0.0f,S1=0.0f,S2=0.0f,S3=0.0f;
#define P1E(LV, SS, IDX) { \
    float l_ = (LV); u32 k_ = f2key(l_); \
    if (k_ > km) km = k_; \
    SS += __expf(l_ * invT); \
    if (k_ >= keyspec){ \
      atomicAdd(&cnt[k_>>20], 1u); \
      u32 p_ = atomicAdd(&sh_len, 1u); \
      if (p_ < CAPL) list[p_] = ((u64)k_ << 32) | (u64)(u32)(IDX); \
    } }
  for (int i=t; i<NV4; i+=2*BLK){
    float4 qa = row4[i];
    int i2 = i + BLK; bool h2 = (i2 < NV4);
    float4 qb; if (h2) qb = row4[i2];
    P1E(qa.x,S0,i*4+0) P1E(qa.y,S1,i*4+1) P1E(qa.z,S2,i*4+2) P1E(qa.w,S3,i*4+3)
    if (h2){
      P1E(qb.x,S0,i2*4+0) P1E(qb.y,S1,i2*4+1) P1E(qb.z,S2,i2*4+2) P1E(qb.w,S3,i2*4+3)
    }
  }
#undef P1E
  float S = (S0+S1)+(S2+S3);
  #pragma unroll
  for (int d=32; d>0; d>>=1){
    S += __shfl_down(S, d, 64);
    u32 k2 = __shfl_down(km, d, 64); if (k2 > km) km = k2;
  }
  if (ln==0){ wrf1[wv]=S; wru1[wv]=km; }
  __syncthreads();                        // orders hist atomics + sh_len
  if (t==0){
    float St=0.0f; u32 kt=0u;
    for (int w=0; w<NW; w++){ St += wrf1[w]; if (wru1[w]>kt) kt=wru1[w]; }
    sh_kmax = kt;
    sh_Z = St;
  }
  __syncthreads();
  const float m = key2f(sh_kmax) * invT;
  const float Z = sh_Z * __expf(-m);
  const u32 Nc = sh_len;                  // exact count of tokens in buckets >= bspec

  int tk = topk[b]; if (tk < 1) tk = 1; if (tk > VOCAB) tk = VOCAB;
  const bool sampleOK = (Nc >= (u32)tk);
  u32 NcEff = Nc;
  if (!sampleOK){
    // corrective full count hist (~never taken)
    __syncthreads();
    for (int i=t;i<NB;i+=BLK) cnt[i]=0u;
    __syncthreads();
    for (int i=t; i<NV4; i+=BLK){
      float4 q = row4[i];
      #pragma unroll
      for (int j=0;j<4;j++) atomicAdd(&cnt[f2key((&q.x)[j])>>20], 1u);
    }
    __syncthreads();
    NcEff = (u32)VOCAB;
  }

  // ---- top-k level-1 crossing over counted hist ----
  cross4096_u32(cnt, aux32, NcEff - (u32)tk, &sh_idx, &sh_bef32, t);
  __syncthreads();
  const u32 b1k = sh_idx;
  const u32 r1  = (NcEff - (u32)tk + 1u) - sh_bef32;

  // ---- min-p raw cutoff l*: wave-parallel monotone search ----
  if (wv==0){
    const float rhs = minp[b] * (1.0f / Z);
    u32 lo = 0u, hi = 0xFF800000u;       // pred(hi)=true; pred(0)=false (NaN key)
    while (hi - lo > 64u){
      u32 step = (hi - lo) >> 6;
      u32 k = lo + (u32)(ln + 1) * step;
      float e = __expf(fmaf(key2f(k), invT, -m));
      u64 bal = __ballot((e / Z) >= rhs);
      if (bal){
        u32 g = (u32)(__ffsll((long long)bal) - 1);
        hi = lo + (g + 1u) * step;
        lo = lo + g * step;
      } else {
        lo += 64u * step;
      }
    }
    u32 k = lo + 1u + (u32)ln;
    bool ok = (k <= hi);
    float e = __expf(fmaf(key2f(k), invT, -m));
    u64 bal = __ballot(ok && ((e / Z) >= rhs));
    if (ln==0) sh_lstar = bal ? (lo + 1u + (u32)(__ffsll((long long)bal) - 1)) : hi;
  }
  __syncthreads();
  const u32 lstar = sh_lstar;
  const bool fastOK = sampleOK && (Nc <= (u32)CAPL);
  const float cs = LN2X40 - m;           // (u64)expf(l*invT + cs) = e^(s-m)*2^40

  // ======== P2: filtered mass hist + K (no list work) ========
  u32 kc = 0u;
#define P2E(LV) { \
    float l_ = (LV); u32 key_ = f2key(l_); \
    if (key_ >= lstar){ \
      kc++; \
      u64 lm_ = (u64)__expf(fmaf(l_, invT, cs)); \
      if (lm_) atomicAdd(&massI[key_>>20], lm_); \
    } }
  for (int i=t; i<NV4; i+=2*BLK){
    float4 qa = row4[i];
    int i2 = i + BLK; bool h2 = (i2 < NV4);
    float4 qb; if (h2) qb = row4[i2];
    P2E(qa.x) P2E(qa.y) P2E(qa.z) P2E(qa.w)
    if (h2){ P2E(qb.x) P2E(qb.y) P2E(qb.z) P2E(qb.w) }
  }
#undef P2E
  #pragma unroll
  for (int d=32; d>0; d>>=1) kc += __shfl_down(kc, d, 64);
  if (ln==0) wru2[wv] = kc;
  __syncthreads();                        // P2 atomics complete here
  if (t==0){ u32 K2=0u; for (int w=0;w<NW;w++) K2 += wru2[w]; wru2[0] = K2; }
  __syncthreads();
  const u32 K = wru2[0];
  const bool kval = (K >= (u32)tk);

  cross4096_mass(massI, aux64, topp[b], &sh_tfix, &sh_idx, &sh_bef64, t);
  __syncthreads();
  const u32 b1p = sh_idx;
  const u64 t1  = sh_tfix - sh_bef64;
  const bool needK = kval && (b1p <= b1k);
  const bool needP = (!kval) || (b1p >= b1k);
  // p-refinement requires bucket b1p fully present in list
  const bool canfast = fastOK && !(needP && (b1p < bspec));

  u32 kkey = 0u, pkey = 0u;

  if (canfast){
    const u32 llen = Nc;
    // ---- k-refine from list ----
    if (needK){
      for (int i=t;i<NB;i+=BLK) cnt[i]=0u;
      __syncthreads();
      for (u32 i=t; i<llen; i+=BLK){
        u32 key = (u32)(list[i]>>32);
        if ((key>>20) == b1k) atomicAdd(&cnt[(key>>8)&0xFFFu], 1u);
      }
      __syncthreads();
      cross4096_u32(cnt, aux32, r1-1u, &sh_idx, &sh_bef32, t);
      __syncthreads();
      u32 b2k = sh_idx, r2 = r1 - sh_bef32;
      u32 prefk = (b1k<<12) | b2k;
      for (int i=t;i<256;i+=BLK) cnt[i]=0u;
      __syncthreads();
      for (u32 i=t; i<llen; i+=BLK){
        u32 key = (u32)(list[i]>>32);
        if ((key>>8) == prefk) atomicAdd(&cnt[key&0xFFu], 1u);
      }
      __syncthreads();
      cross256_u32(cnt, r2-1u, &sh_idx, t);
      __syncthreads();
      kkey = (prefk<<8) | sh_idx;
    }
    // ---- p-refine from list ----
    if (needP){
      for (int i=t;i<NB;i+=BLK) massI[i]=0ull;
      __syncthreads();
      for (u32 i=t; i<llen; i+=BLK){
        u32 key = (u32)(list[i]>>32);
        if ((key>>20) == b1p && key >= lstar){
          u64 lm = (u64)__expf(fmaf(key2f(key), invT, cs));
          if (lm) atomicAdd(&massI[(key>>8)&0xFFFu], lm);
        }
      }
      __syncthreads();
      cross4096_u64(massI, aux64, t1, &sh_idx, &sh_bef64, t);
      __syncthreads();
      u32 b2p = sh_idx; u64 t2 = t1 - sh_bef64;
      u32 prefp = (b1p<<12) | b2p;
      for (int i=t;i<256;i+=BLK) massI[i]=0ull;
      __syncthreads();
      for (u32 i=t; i<llen; i+=BLK){
        u32 key = (u32)(list[i]>>32);
        if ((key>>8) == prefp && key >= lstar){
          u64 lm = (u64)__expf(fmaf(key2f(key), invT, cs));
          if (lm) atomicAdd(&massI[key&0xFFu], lm);
        }
      }
      __syncthreads();
      cross256_u64(massI, t2, &sh_idx, t);
      __syncthreads();
      pkey = (prefp<<8) | sh_idx;
    }
    const u32 thrkey = kkey > pkey ? kkey : pkey;

    // ---- sampling over list (survivors <= ~63; thrkey >= keyspec so all in list) ----
    float best = -INFINITY; u32 bi = 0xFFFFFFFFu;
    for (u32 i=t; i<llen; i+=BLK){
      u64 e = list[i];
      u32 key = (u32)(e>>32);
      if (key >= thrkey){
        u32 idx = (u32)e;
        u32 c = (u32)b * (u32)VOCAB + idx;
        float cand = key2f(key)*invT + bits2gumbel(gumbel_bits(c));
        if (cand > best || (cand == best && idx < bi)){ best = cand; bi = idx; }
      }
    }
    argmax_write(best, bi, wrf1, wru1, ln, wv, b, out);
    return;
  }

  // ======== slow path (overflow / sample failure / uncovered b1p) ========
  for (int i=t;i<NB;i+=BLK){ cnt[i]=0u; massI[i]=0ull; }
  __syncthreads();
  for (int i=t; i<NV4; i+=BLK){
    float4 q = row4[i];
    #pragma unroll
    for (int j=0;j<4;j++){
      float l = (&q.x)[j]; u32 key = f2key(l); u32 hb = key>>20;
      if (needK && hb == b1k) atomicAdd(&cnt[(key>>8)&0xFFFu], 1u);
      if (needP && hb == b1p && key >= lstar){
        u64 lm = (u64)__expf(fmaf(l, invT, cs));
        if (lm) atomicAdd(&massI[(key>>8)&0xFFFu], lm);
      }
    }
  }
  __syncthreads();
  u32 b2k = 0u, r2 = 1u, b2p = 0u; u64 t2 = 0ull;
  if (needK){
    cross4096_u32(cnt, aux32, r1-1u, &sh_idx, &sh_bef32, t);
    __syncthreads();
    b2k = sh_idx; r2 = r1 - sh_bef32;
  }
  if (needP){
    cross4096_u64(massI, aux64, t1, &sh_idx, &sh_bef64, t);
    __syncthreads();
    b2p = sh_idx; t2 = t1 - sh_bef64;
  }
  const u32 prefk = (b1k<<12) | b2k;
  const u32 prefp = (b1p<<12) | b2p;
  for (int i=t;i<256;i+=BLK){ cnt[i]=0u; massI[i]=0ull; }
  __syncthreads();
  for (int i=t; i<NV4; i+=BLK){
    float4 q = row4[i];
    #pragma unroll
    for (int j=0;j<4;j++){
      float l = (&q.x)[j]; u32 key = f2key(l);
      if (needK && (key>>8) == prefk) atomicAdd(&cnt[key&0xFFu], 1u);
      if (needP && (key>>8) == prefp && key >= lstar){
        u64 lm = (u64)__expf(fmaf(l, invT, cs));
        if (lm) atomicAdd(&massI[key&0xFFu], lm);
      }
    }
  }
  __syncthreads();
  if (needK){
    cross256_u32(cnt, r2-1u, &sh_idx, t);
    __syncthreads();
    kkey = (prefk<<8) | sh_idx;
  }
  if (needP){
    cross256_u64(massI, t2, &sh_idx, t);
    __syncthreads();
    pkey = (prefp<<8) | sh_idx;
  }
  const float thrf = key2f(kkey > pkey ? kkey : pkey);
  float best = -INFINITY; u32 bi = 0xFFFFFFFFu;
  for (int i=t; i<NV4; i+=BLK){
    float4 q = row4[i];
    #pragma unroll
    for (int j=0;j<4;j++){
      float l = (&q.x)[j];
      if (l >= thrf){
        u32 idx = (u32)(i*4+j);
        u32 c = (u32)b * (u32)VOCAB + idx;
        float cand = l*invT + bits2gumbel(gumbel_bits(c));
        if (cand > best || (cand == best && idx < bi)){ best = cand; bi = idx; }
      }
    }
  }
  argmax_write(best, bi, wrf1, wru1, ln, wv, b, out);
}

extern "C" void kernel_launch(void* const* d_in, const int* in_sizes, int n_in,
                              void* d_out, int out_size, void* d_ws, size_t ws_size,
                              hipStream_t stream)
{
  const float* logits = (const float*)d_in[0];
  const float* temp   = (const float*)d_in[1];
  const float* minp   = (const float*)d_in[2];
  const int*   topk   = (const int*)d_in[3];
  const float* topp   = (const float*)d_in[4];
  int* out = (int*)d_out;

  hipLaunchKernelGGL(k_all, dim3(NROWS), dim3(BLK), 0, stream,
                     logits, temp, minp, topk, topp, out);
}

// Round 16
// 57.214 us; speedup vs baseline: 1.2816x; 1.1388x over previous
//
#include <hip/hip_runtime.h>
#include <stdint.h>

typedef unsigned long long u64;
typedef unsigned int u32;

#define VOCAB 128000
#define NV4   32000      // VOCAB/4
#define NROWS 256
#define BLK   1024
#define NW    16
#define NB    4096
#define CAPL  2048       // list capacity (exact precheck + proven slow path)
#define SEPS  1e-5f
#define LN2X40 27.725887222397812f   /* 40*ln2 */

// ---------- helpers ----------
__device__ __forceinline__ u32 f2key(float f){
  u32 u = __float_as_uint(f);
  return (u & 0x80000000u) ? ~u : (u | 0x80000000u);   // order-preserving
}
__device__ __forceinline__ float key2f(u32 k){
  u32 u = (k & 0x80000000u) ? (k ^ 0x80000000u) : ~k;
  return __uint_as_float(u);
}

// JAX threefry2x32, key (0,42)
__device__ __forceinline__ void tf2x32(u32 x0, u32 x1, u32 &o0, u32 &o1){
  const u32 k0 = 0u, k1 = 42u, k2 = 0u ^ 42u ^ 0x1BD11BDAu;
  x0 += k0; x1 += k1;
#define TFR(r) { x0 += x1; x1 = (x1 << (r)) | (x1 >> (32 - (r))); x1 ^= x0; }
  TFR(13) TFR(15) TFR(26) TFR(6)
  x0 += k1; x1 += k2 + 1u;
  TFR(17) TFR(29) TFR(16) TFR(24)
  x0 += k2; x1 += k0 + 2u;
  TFR(13) TFR(15) TFR(26) TFR(6)
  x0 += k0; x1 += k1 + 3u;
  TFR(17) TFR(29) TFR(16) TFR(24)
  x0 += k1; x1 += k2 + 4u;
  TFR(13) TFR(15) TFR(26) TFR(6)
  x0 += k2; x1 += k0 + 5u;
#undef TFR
  o0 = x0; o1 = x1;
}
__device__ __forceinline__ u32 gumbel_bits(u32 i){
  u32 o0, o1; tf2x32(0u, i, o0, o1);
  return o0 ^ o1;
}
__device__ __forceinline__ float bits2gumbel(u32 b){
  float f = __uint_as_float(0x3F800000u | (b >> 9)) - 1.0f;  // [0,1)
  float u = fmaxf(1e-10f, f + 1e-10f);
  return -logf(-logf(u));
}

// ---------- crossing searches (reduce + wave-0 descent) ----------
__device__ __forceinline__ void cross4096_u32(
    const u32* arr, u32* aux, u32 target, u32* out_idx, u32* out_before, int t)
{
  aux[t] = arr[4*t+0] + arr[4*t+1] + arr[4*t+2] + arr[4*t+3];
  __syncthreads();
  if (t < 64){
    u32 gs = 0u;
    #pragma unroll
    for (int j=0;j<16;j++) gs += aux[t*16+j];
    u32 pref = gs;
    #pragma unroll
    for (int d=1; d<64; d<<=1){ u32 v = __shfl_up(pref, d, 64); if (t >= d) pref += v; }
    u64 bal = __ballot(pref > target);
    int g = bal ? (__ffsll((long long)bal) - 1) : 63;
    u32 pg = __shfl(pref, g, 64);
    u32 gg = __shfl(gs, g, 64);
    if (t == 0){
      u32 c = pg - gg;
      u32 idx = (u32)(g*64 + 63);
      for (int j=0;j<16;j++){
        u32 v = aux[g*16+j];
        if (c + v > target){
          int base = (g*16+j)*4;
          for (int q=0;q<4;q++){
            u32 w = arr[base+q];
            if (c + w > target){ idx = (u32)(base+q); goto doneu; }
            c += w;
          }
        }
        c += v;
      }
      doneu:
      *out_idx = idx; *out_before = c;
    }
  }
}

__device__ __forceinline__ void cross4096_u64(
    const u64* arr, u64* aux, u64 target, u32* out_idx, u64* out_before, int t)
{
  aux[t] = arr[4*t+0] + arr[4*t+1] + arr[4*t+2] + arr[4*t+3];
  __syncthreads();
  if (t < 64){
    u64 gs = 0ull;
    #pragma unroll
    for (int j=0;j<16;j++) gs += aux[t*16+j];
    u64 pref = gs;
    #pragma unroll
    for (int d=1; d<64; d<<=1){
      u64 v = __shfl_up((unsigned long long)pref, d, 64); if (t >= d) pref += v;
    }
    u64 bal = __ballot(pref > target);
    int g = bal ? (__ffsll((long long)bal) - 1) : 63;
    u64 pg = __shfl((unsigned long long)pref, g, 64);
    u64 gg = __shfl((unsigned long long)gs, g, 64);
    if (t == 0){
      u64 c = pg - gg;
      u32 idx = (u32)(g*64 + 63);
      for (int j=0;j<16;j++){
        u64 v = aux[g*16+j];
        if (c + v > target){
          int base = (g*16+j)*4;
          for (int q=0;q<4;q++){
            u64 w = arr[base+q];
            if (c + w > target){ idx = (u32)(base+q); goto donev; }
            c += w;
          }
        }
        c += v;
      }
      donev:
      *out_idx = idx; *out_before = c;
    }
  }
}

// level-1 mass: derives total and target = (1-topp)*total internally
__device__ __forceinline__ void cross4096_mass(
    const u64* arr, u64* aux, float topp_v, u64* out_target,
    u32* out_idx, u64* out_before, int t)
{
  aux[t] = arr[4*t+0] + arr[4*t+1] + arr[4*t+2] + arr[4*t+3];
  __syncthreads();
  if (t < 64){
    u64 gs = 0ull;
    #pragma unroll
    for (int j=0;j<16;j++) gs += aux[t*16+j];
    u64 pref = gs;
    #pragma unroll
    for (int d=1; d<64; d<<=1){
      u64 v = __shfl_up((unsigned long long)pref, d, 64); if (t >= d) pref += v;
    }
    u64 total = __shfl((unsigned long long)pref, 63, 64);
    u64 target = (u64)((double)(1.0f - topp_v) * (double)total);
    u64 bal = __ballot(pref > target);
    int g = bal ? (__ffsll((long long)bal) - 1) : 63;
    u64 pg = __shfl((unsigned long long)pref, g, 64);
    u64 gg = __shfl((unsigned long long)gs, g, 64);
    if (t == 0){
      u64 c = pg - gg;
      u32 idx = (u32)(g*64 + 63);
      for (int j=0;j<16;j++){
        u64 v = aux[g*16+j];
        if (c + v > target){
          int base = (g*16+j)*4;
          for (int q=0;q<4;q++){
            u64 w = arr[base+q];
            if (c + w > target){ idx = (u32)(base+q); goto donem; }
            c += w;
          }
        }
        c += v;
      }
      donem:
      *out_target = target; *out_idx = idx; *out_before = c;
    }
  }
}

__device__ __forceinline__ void cross256_u32(const u32* arr, u32 target, u32* out_idx, int t){
  if (t < 64){
    u32 gs = arr[4*t+0]+arr[4*t+1]+arr[4*t+2]+arr[4*t+3];
    u32 pref = gs;
    #pragma unroll
    for (int d=1; d<64; d<<=1){ u32 v=__shfl_up(pref,d,64); if (t>=d) pref+=v; }
    u64 bal = __ballot(pref > target);
    int g = bal ? (__ffsll((long long)bal)-1) : 63;
    u32 pg=__shfl(pref,g,64), gg=__shfl(gs,g,64);
    if (t==0){
      u32 c = pg-gg; u32 idx=(u32)(g*4+3);
      for (int q=0;q<4;q++){ u32 w=arr[g*4+q]; if (c+w>target){ idx=(u32)(g*4+q); break; } c+=w; }
      *out_idx = idx;
    }
  }
}
__device__ __forceinline__ void cross256_u64(const u64* arr, u64 target, u32* out_idx, int t){
  if (t < 64){
    u64 gs = arr[4*t+0]+arr[4*t+1]+arr[4*t+2]+arr[4*t+3];
    u64 pref = gs;
    #pragma unroll
    for (int d=1; d<64; d<<=1){
      u64 v=__shfl_up((unsigned long long)pref,d,64); if (t>=d) pref+=v;
    }
    u64 bal = __ballot(pref > target);
    int g = bal ? (__ffsll((long long)bal)-1) : 63;
    u64 pg=__shfl((unsigned long long)pref,g,64), gg=__shfl((unsigned long long)gs,g,64);
    if (t==0){
      u64 c = pg-gg; u32 idx=(u32)(g*4+3);
      for (int q=0;q<4;q++){ u64 w=arr[g*4+q]; if (c+w>target){ idx=(u32)(g*4+q); break; } c+=w; }
      *out_idx = idx;
    }
  }
}

// block argmax (larger value, then smaller idx) -> out[b]
__device__ __forceinline__ void argmax_write(
    float best, u32 bi, float* wrf, u32* wru, int ln, int wv, int b, int* out)
{
  #pragma unroll
  for (int d=32; d>0; d>>=1){
    float c2=__shfl_down(best,d,64); u32 i2=__shfl_down(bi,d,64);
    if (c2>best || (c2==best && i2<bi)){best=c2;bi=i2;}
  }
  if (ln==0){ wrf[wv]=best; wru[wv]=bi; }
  __syncthreads();
  if (wv==0){
    float b1=(ln<NW)?wrf[ln]:-INFINITY; u32 i1=(ln<NW)?wru[ln]:0xFFFFFFFFu;
    #pragma unroll
    for (int d=32; d>0; d>>=1){
      float b2=__shfl_down(b1,d,64); u32 i2=__shfl_down(i1,d,64);
      if (b2>b1 || (b2==b1 && i2<i1)){b1=b2;i1=i2;}
    }
    if (ln==0) out[b]=(int)i1;
  }
}

// ---------- fused kernel: one block per row ----------
__global__ __launch_bounds__(BLK) void k_all(
    const float* __restrict__ logits, const float* __restrict__ temp,
    const float* __restrict__ minp, const int* __restrict__ topk,
    const float* __restrict__ topp, int* __restrict__ out)
{
  __shared__ u32 cnt[NB];          // 16KB
  __shared__ u64 massI[NB];        // 32KB
  __shared__ u64 list[CAPL];       // 16KB
  __shared__ u64 aux64[BLK];       // 8KB scratch (u32-punned too)
  __shared__ float wrf1[NW];
  __shared__ u32  wru1[NW], wru2[NW];
  __shared__ u32 sh_kmax, sh_lstar, sh_len, sh_idx, sh_bef32, sh_u1, sh_u2, sh_u3;
  __shared__ float sh_Z;
  __shared__ u64 sh_bef64, sh_tfix;

  u32* aux32 = (u32*)aux64;

  const int b = blockIdx.x;
  const int t = threadIdx.x;
  const int ln = t & 63, wv = t >> 6;
  const float T = temp[b];
  const float* row = logits + (size_t)b * VOCAB;
  const float4* row4 = (const float4*)row;

  // ======== greedy rows: argmax only (1 stream) ========
  if (T < SEPS){
    float M = -INFINITY; u32 Mi = 0xFFFFFFFFu;
    for (int i=t; i<NV4; i+=BLK){
      float4 q = row4[i];
      #pragma unroll
      for (int j=0;j<4;j++){
        float l = (&q.x)[j]; u32 gi = (u32)(i*4+j);
        if (l > M){ M = l; Mi = gi; }
      }
    }
    argmax_write(M, Mi, wrf1, wru1, ln, wv, b, out);
    return;
  }

  // ======== P1: count hist + register Z-sum + key-max (chain-free) ========
  const float invT = 1.0f / T;
  for (int i=t;i<NB;i+=BLK){ cnt[i]=0u; massI[i]=0ull; }
  if (t==0) sh_len=0u;
  __syncthreads();

  u32 km = 0u;
  float S0=0.0f,S1=0.0f,S2=0.0f,S3=0.0f;
#define P1E(LV, SS) { \
    float l_ = (LV); u32 k_ = f2key(l_); \
    if (k_ > km) km = k_; \
    atomicAdd(&cnt[k_>>20], 1u); \
    SS += __expf(l_ * invT); }
  for (int i=t; i<NV4; i+=2*BLK){
    float4 qa = row4[i];
    int i2 = i + BLK; bool h2 = (i2 < NV4);
    float4 qb; if (h2) qb = row4[i2];
    P1E(qa.x,S0) P1E(qa.y,S1) P1E(qa.z,S2) P1E(qa.w,S3)
    if (h2){ P1E(qb.x,S0) P1E(qb.y,S1) P1E(qb.z,S2) P1E(qb.w,S3) }
  }
#undef P1E
  float S = (S0+S1)+(S2+S3);
  #pragma unroll
  for (int d=32; d>0; d>>=1){
    S += __shfl_down(S, d, 64);
    u32 k2 = __shfl_down(km, d, 64); if (k2 > km) km = k2;
  }
  if (ln==0){ wrf1[wv]=S; wru1[wv]=km; }
  __syncthreads();                        // also orders P1 hist atomics
  if (t==0){
    float St=0.0f; u32 kt=0u;
    for (int w=0; w<NW; w++){ St += wrf1[w]; if (wru1[w]>kt) kt=wru1[w]; }
    sh_kmax = kt;
    sh_Z = St;                            // Z' = sum e^{s}; Z = Z' * e^{-m}
  }
  __syncthreads();
  const float m = key2f(sh_kmax) * invT;
  const float Z = sh_Z * __expf(-m);

  // ---- top-k level-1 crossing over all-token counts ----
  int tk = topk[b]; if (tk < 1) tk = 1; if (tk > VOCAB) tk = VOCAB;
  cross4096_u32(cnt, aux32, (u32)(VOCAB - tk), &sh_idx, &sh_bef32, t);
  __syncthreads();
  const u32 b1k = sh_idx;
  const u32 r1  = (u32)(VOCAB - tk + 1) - sh_bef32;

  // ---- min-p raw cutoff l*: wave-parallel monotone search ----
  if (wv==0){
    const float rhs = minp[b] * (1.0f / Z);
    u32 lo = 0u, hi = 0xFF800000u;       // pred(hi)=true; pred(0)=false (NaN key)
    while (hi - lo > 64u){
      u32 step = (hi - lo) >> 6;
      u32 k = lo + (u32)(ln + 1) * step;
      float e = __expf(fmaf(key2f(k), invT, -m));
      u64 bal = __ballot((e / Z) >= rhs);
      if (bal){
        u32 g = (u32)(__ffsll((long long)bal) - 1);
        hi = lo + (g + 1u) * step;
        lo = lo + g * step;
      } else {
        lo += 64u * step;
      }
    }
    u32 k = lo + 1u + (u32)ln;
    bool ok = (k <= hi);
    float e = __expf(fmaf(key2f(k), invT, -m));
    u64 bal = __ballot(ok && ((e / Z) >= rhs));
    if (ln==0) sh_lstar = bal ? (lo + 1u + (u32)(__ffsll((long long)bal) - 1)) : hi;
  }
  __syncthreads();
  const u32 lstar = sh_lstar;
  const u32 bl = lstar >> 20;

  // ---- Kmin (#tokens buckets > bl), pc (#tokens buckets >= b1k) ----
  {
    u32 pa=0u, pc=0u;
    for (int i=t;i<NB;i+=BLK){
      u32 c = cnt[i];
      if ((u32)i > bl)   pa += c;
      if ((u32)i >= b1k) pc += c;
    }
    #pragma unroll
    for (int d=32; d>0; d>>=1){ pa += __shfl_down(pa,d,64); pc += __shfl_down(pc,d,64); }
    if (ln==0){ wru1[wv]=pa; wru2[wv]=pc; }
    __syncthreads();
    if (t==0){
      u32 a=0u, c2=0u;
      for (int w=0; w<NW; w++){ a += wru1[w]; c2 += wru2[w]; }
      sh_u1 = a; sh_u2 = c2;
    }
    __syncthreads();
  }
  const u32 Kmin = sh_u1;
  const bool kcert = (Kmin >= (u32)tk);
  const u32 CLB = kcert ? b1k : bl;      // if !kcert and kval: b1k==bl (proven r5)
  const u32 listlen = kcert ? sh_u2 : (Kmin + cnt[bl]);
  const bool fastOK = (listlen <= (u32)CAPL);
  const float cs = LN2X40 - m;           // (u64)expf(l*invT + cs) = e^(s-m)*2^40

  // ======== P2: filtered mass hist + K + compaction ========
  u32 kc = 0u;
#define P2E(LV, IDX) { \
    float l_ = (LV); u32 key_ = f2key(l_); \
    if (key_ >= lstar){ \
      kc++; \
      u64 lm_ = (u64)__expf(fmaf(l_, invT, cs)); \
      if (lm_) atomicAdd(&massI[key_>>20], lm_); \
    } \
    if (fastOK && (key_>>20) >= CLB){ \
      u32 p_ = atomicAdd(&sh_len, 1u); \
      if (p_ < CAPL) list[p_] = ((u64)key_ << 32) | (u64)(u32)(IDX); \
    } \
  }
  for (int i=t; i<NV4; i+=2*BLK){
    float4 qa = row4[i];
    int i2 = i + BLK; bool h2 = (i2 < NV4);
    float4 qb; if (h2) qb = row4[i2];
    P2E(qa.x, i*4+0) P2E(qa.y, i*4+1) P2E(qa.z, i*4+2) P2E(qa.w, i*4+3)
    if (h2){
      P2E(qb.x, i2*4+0) P2E(qb.y, i2*4+1) P2E(qb.z, i2*4+2) P2E(qb.w, i2*4+3)
    }
  }
#undef P2E
  #pragma unroll
  for (int d=32; d>0; d>>=1) kc += __shfl_down(kc, d, 64);
  if (ln==0) wru1[wv] = kc;
  __syncthreads();                        // P2 atomics complete here
  if (t==0){ u32 K2=0u; for (int w=0;w<NW;w++) K2 += wru1[w]; sh_u3 = K2; }
  __syncthreads();
  const u32 K = sh_u3;
  const bool kval = (K >= (u32)tk);
  const u32 llen = (sh_len <= (u32)CAPL) ? sh_len : (u32)CAPL;

  cross4096_mass(massI, aux64, topp[b], &sh_tfix, &sh_idx, &sh_bef64, t);
  __syncthreads();
  const u32 b1p = sh_idx;
  const u64 t1  = sh_tfix - sh_bef64;
  const bool needK = kval && (b1p <= b1k);
  const bool needP = (!kval) || (b1p >= b1k);

  u32 kkey = 0u, pkey = 0u;

  if (fastOK){
    // ---- k-refine from list ----
    if (needK){
      for (int i=t;i<NB;i+=BLK) cnt[i]=0u;
      __syncthreads();
      for (u32 i=t; i<llen; i+=BLK){
        u32 key = (u32)(list[i]>>32);
        if ((key>>20) == b1k) atomicAdd(&cnt[(key>>8)&0xFFFu], 1u);
      }
      __syncthreads();
      cross4096_u32(cnt, aux32, r1-1u, &sh_idx, &sh_bef32, t);
      __syncthreads();
      u32 b2k = sh_idx, r2 = r1 - sh_bef32;
      u32 prefk = (b1k<<12) | b2k;
      for (int i=t;i<256;i+=BLK) cnt[i]=0u;
      __syncthreads();
      for (u32 i=t; i<llen; i+=BLK){
        u32 key = (u32)(list[i]>>32);
        if ((key>>8) == prefk) atomicAdd(&cnt[key&0xFFu], 1u);
      }
      __syncthreads();
      cross256_u32(cnt, r2-1u, &sh_idx, t);
      __syncthreads();
      kkey = (prefk<<8) | sh_idx;
    }
    // ---- p-refine from list ----
    if (needP){
      for (int i=t;i<NB;i+=BLK) massI[i]=0ull;
      __syncthreads();
      for (u32 i=t; i<llen; i+=BLK){
        u32 key = (u32)(list[i]>>32);
        if ((key>>20) == b1p && key >= lstar){
          u64 lm = (u64)__expf(fmaf(key2f(key), invT, cs));
          if (lm) atomicAdd(&massI[(key>>8)&0xFFFu], lm);
        }
      }
      __syncthreads();
      cross4096_u64(massI, aux64, t1, &sh_idx, &sh_bef64, t);
      __syncthreads();
      u32 b2p = sh_idx; u64 t2 = t1 - sh_bef64;
      u32 prefp = (b1p<<12) | b2p;
      for (int i=t;i<256;i+=BLK) massI[i]=0ull;
      __syncthreads();
      for (u32 i=t; i<llen; i+=BLK){
        u32 key = (u32)(list[i]>>32);
        if ((key>>8) == prefp && key >= lstar){
          u64 lm = (u64)__expf(fmaf(key2f(key), invT, cs));
          if (lm) atomicAdd(&massI[key&0xFFu], lm);
        }
      }
      __syncthreads();
      cross256_u64(massI, t2, &sh_idx, t);
      __syncthreads();
      pkey = (prefp<<8) | sh_idx;
    }
    const u32 thrkey = kkey > pkey ? kkey : pkey;

    // ---- sampling over list (survivors <= ~63) ----
    float best = -INFINITY; u32 bi = 0xFFFFFFFFu;
    for (u32 i=t; i<llen; i+=BLK){
      u64 e = list[i];
      u32 key = (u32)(e>>32);
      if (key >= thrkey){
        u32 idx = (u32)e;
        u32 c = (u32)b * (u32)VOCAB + idx;
        float cand = key2f(key)*invT + bits2gumbel(gumbel_bits(c));
        if (cand > best || (cand == best && idx < bi)){ best = cand; bi = idx; }
      }
    }
    argmax_write(best, bi, wrf1, wru1, ln, wv, b, out);
    return;
  }

  // ======== slow path (list overflow): full-stream refinement + sampling ========
  for (int i=t;i<NB;i+=BLK){ cnt[i]=0u; massI[i]=0ull; }
  __syncthreads();
  for (int i=t; i<NV4; i+=BLK){
    float4 q = row4[i];
    #pragma unroll
    for (int j=0;j<4;j++){
      float l = (&q.x)[j]; u32 key = f2key(l); u32 hb = key>>20;
      if (needK && hb == b1k) atomicAdd(&cnt[(key>>8)&0xFFFu], 1u);
      if (needP && hb == b1p && key >= lstar){
        u64 lm = (u64)__expf(fmaf(l, invT, cs));
        if (lm) atomicAdd(&massI[(key>>8)&0xFFFu], lm);
      }
    }
  }
  __syncthreads();
  u32 b2k = 0u, r2 = 1u, b2p = 0u; u64 t2 = 0ull;
  if (needK){
    cross4096_u32(cnt, aux32, r1-1u, &sh_idx, &sh_bef32, t);
    __syncthreads();
    b2k = sh_idx; r2 = r1 - sh_bef32;
  }
  if (needP){
    cross4096_u64(massI, aux64, t1, &sh_idx, &sh_bef64, t);
    __syncthreads();
    b2p = sh_idx; t2 = t1 - sh_bef64;
  }
  const u32 prefk = (b1k<<12) | b2k;
  const u32 prefp = (b1p<<12) | b2p;
  for (int i=t;i<256;i+=BLK){ cnt[i]=0u; massI[i]=0ull; }
  __syncthreads();
  for (int i=t; i<NV4; i+=BLK){
    float4 q = row4[i];
    #pragma unroll
    for (int j=0;j<4;j++){
      float l = (&q.x)[j]; u32 key = f2key(l);
      if (needK && (key>>8) == prefk) atomicAdd(&cnt[key&0xFFu], 1u);
      if (needP && (key>>8) == prefp && key >= lstar){
        u64 lm = (u64)__expf(fmaf(l, invT, cs));
        if (lm) atomicAdd(&massI[key&0xFFu], lm);
      }
    }
  }
  __syncthreads();
  if (needK){
    cross256_u32(cnt, r2-1u, &sh_idx, t);
    __syncthreads();
    kkey = (prefk<<8) | sh_idx;
  }
  if (needP){
    cross256_u64(massI, t2, &sh_idx, t);
    __syncthreads();
    pkey = (prefp<<8) | sh_idx;
  }
  const float thrf = key2f(kkey > pkey ? kkey : pkey);
  float best = -INFINITY; u32 bi = 0xFFFFFFFFu;
  for (int i=t; i<NV4; i+=BLK){
    float4 q = row4[i];
    #pragma unroll
    for (int j=0;j<4;j++){
      float l = (&q.x)[j];
      if (l >= thrf){
        u32 idx = (u32)(i*4+j);
        u32 c = (u32)b * (u32)VOCAB + idx;
        float cand = l*invT + bits2gumbel(gumbel_bits(c));
        if (cand > best || (cand == best && idx < bi)){ best = cand; bi = idx; }
      }
    }
  }
  argmax_write(best, bi, wrf1, wru1, ln, wv, b, out);
}

extern "C" void kernel_launch(void* const* d_in, const int* in_sizes, int n_in,
                              void* d_out, int out_size, void* d_ws, size_t ws_size,
                              hipStream_t stream)
{
  const float* logits = (const float*)d_in[0];
  const float* temp   = (const float*)d_in[1];
  const float* minp   = (const float*)d_in[2];
  const int*   topk   = (const int*)d_in[3];
  const float* topp   = (const float*)d_in[4];
  int* out = (int*)d_out;

  hipLaunchKernelGGL(k_all, dim3(NROWS), dim3(BLK), 0, stream,
                     logits, temp, minp, topk, topp, out);
}